// Round 9
// baseline (219.347 us; speedup 1.0000x reference)
//
#include <hip/hip_runtime.h>
#include <math.h>

#define N_NODES 100000
#define N_EDGES 1600000
#define NB_BANK 1000
#define N_PAIRS 500000

#define BUCK_SHIFT 9
#define BUCK_NODES 512
#define NBUCK 196            // ceil(N_NODES/512)
#define BCAP 10240           // fixed ebuf/csr stride per bucket (mean 8163 + 22 sigma)
#define EPB 16384            // edges per scatter block
#define NSCAT 98             // ceil(N_EDGES/EPB)
#define NZBLK 1954           // ceil(N_PAIRS/256)
#define SMASK 0x1FFFF        // low 17 bits = src id (N_NODES < 2^17)

struct Consts {
  float C[27*8];    // [P1|P2] : X -> 8 channels
  float Rb[27*8];   // [Wb@Ttop | Wb@Tbot]
  float u[8];       // coefficient of dvec (A-hat * 1)
  float vg[8];      // graph-row constant
  float vb[8];      // bank-row constant
};

// ---- dense weight-chain precompute, runs as the extra block of k_scatter ----
__device__ void precompute_body(
    const float* __restrict__ W1, const float* __restrict__ b1,
    const float* __restrict__ W2, const float* __restrict__ b2,
    const float* __restrict__ Wb, const float* __restrict__ bb,
    const float* __restrict__ Wf1, const float* __restrict__ bf1,
    const float* __restrict__ Wf2, const float* __restrict__ bf2,
    const float* __restrict__ Wf3, const float* __restrict__ bf3,
    Consts* __restrict__ cst) {
  __shared__ float A[40*4];    // Wf2 @ Wf3
  __shared__ float T[100*4];   // Wf1 @ A
  __shared__ float B[60*8];    // W2 @ [Ttop|Tbot]
  __shared__ float cvec[4];
  const int tid = threadIdx.x;
  const int nt = blockDim.x;

  for (int idx = tid; idx < 160; idx += nt) {
    int r = idx >> 2, k = idx & 3;
    float s = 0.f;
    for (int j = 0; j < 20; ++j) s += Wf2[r*20+j] * Wf3[j*4+k];
    A[idx] = s;
  }
  __syncthreads();
  for (int idx = tid; idx < 400; idx += nt) {
    int r = idx >> 2, k = idx & 3;
    float s = 0.f;
    for (int j = 0; j < 40; ++j) s += Wf1[r*40+j] * A[j*4+k];
    T[idx] = s;
  }
  if (tid < 4) {
    float s = bf3[tid];
    for (int j = 0; j < 40; ++j) s += bf1[j] * A[j*4+tid];
    for (int j = 0; j < 20; ++j) s += bf2[j] * Wf3[j*4+tid];
    cvec[tid] = s;
  }
  __syncthreads();
  for (int idx = tid; idx < 480; idx += nt) {
    int r = idx >> 3, k = idx & 7;
    int half = k >> 2, kk = k & 3;
    float s = 0.f;
    for (int j = 0; j < 50; ++j) s += W2[r*50+j] * T[(half*50+j)*4+kk];
    B[idx] = s;
  }
  __syncthreads();
  for (int idx = tid; idx < 456; idx += nt) {
    if (idx < 216) {                       // C = W1 @ B [27,8]
      int r = idx >> 3, k = idx & 7;
      float s = 0.f;
      for (int j = 0; j < 60; ++j) s += W1[r*60+j] * B[j*8+k];
      cst->C[idx] = s;
    } else if (idx < 432) {                // Rb = Wb @ [Ttop|Tbot] [27,8]
      int i2 = idx - 216;
      int r = i2 >> 3, k = i2 & 7, half = k >> 2, kk = k & 3;
      float s = 0.f;
      for (int j = 0; j < 50; ++j) s += Wb[r*50+j] * T[(half*50+j)*4+kk];
      cst->Rb[i2] = s;
    } else if (idx < 440) {                // u = b1 @ B
      int k = idx - 432;
      float s = 0.f;
      for (int j = 0; j < 60; ++j) s += b1[j] * B[j*8+k];
      cst->u[k] = s;
    } else if (idx < 448) {                // vg = b2 @ [Ttop|Tbot] (+c on half 0)
      int k = idx - 440, half = k >> 2, kk = k & 3;
      float s = (half == 0) ? cvec[kk] : 0.f;
      for (int j = 0; j < 50; ++j) s += b2[j] * T[(half*50+j)*4+kk];
      cst->vg[k] = s;
    } else {                               // vb = bb @ [Ttop|Tbot] (+c on half 0)
      int k = idx - 448, half = k >> 2, kk = k & 3;
      float s = (half == 0) ? cvec[kk] : 0.f;
      for (int j = 0; j < 50; ++j) s += bb[j] * T[(half*50+j)*4+kk];
      cst->vb[k] = s;
    }
  }
}

// --- single-pass bucket scatter into fixed-stride ebuf; bcnt[b] -> counts ----
// dst ids register-cached across the two passes; extra block runs precompute.
__global__ __launch_bounds__(1024) void k_scatter(
    const int* __restrict__ ei, int* __restrict__ bcnt, int* __restrict__ ebuf,
    const float* __restrict__ W1, const float* __restrict__ b1,
    const float* __restrict__ W2, const float* __restrict__ b2,
    const float* __restrict__ Wb, const float* __restrict__ bb,
    const float* __restrict__ Wf1, const float* __restrict__ bf1,
    const float* __restrict__ Wf2, const float* __restrict__ bf2,
    const float* __restrict__ Wf3, const float* __restrict__ bf3,
    Consts* __restrict__ cst) {
  if (blockIdx.x == NSCAT) {   // whole-block branch: safe with __syncthreads
    precompute_body(W1, b1, W2, b2, Wb, bb, Wf1, bf1, Wf2, bf2, Wf3, bf3, cst);
    return;
  }
  __shared__ int hist[NBUCK];
  __shared__ int base[NBUCK];
  const int t = threadIdx.x;
  const int e0 = blockIdx.x * EPB;
  int dcache[EPB / 1024];
  if (t < NBUCK) hist[t] = 0;
  __syncthreads();
#pragma unroll
  for (int i = 0; i < EPB / 1024; ++i) {
    int e = e0 + i * 1024 + t;
    int d = (e < N_EDGES) ? ei[N_EDGES + e] : -1;
    dcache[i] = d;
    if (d >= 0) atomicAdd(&hist[d >> BUCK_SHIFT], 1);
  }
  __syncthreads();
  if (t < NBUCK) {
    int h = hist[t];
    base[t] = h ? (t * BCAP + atomicAdd(&bcnt[t], h)) : 0;
    hist[t] = 0;
  }
  __syncthreads();
#pragma unroll
  for (int i = 0; i < EPB / 1024; ++i) {
    int e = e0 + i * 1024 + t;
    int d = dcache[i];
    if (d >= 0) {
      int s = ei[e];
      int b = d >> BUCK_SHIFT;
      int pos = base[b] + atomicAdd(&hist[b], 1);
      ebuf[pos] = ((d & (BUCK_NODES - 1)) << 17) | s;
    }
  }
}

// -- per-bucket: degree -> dinv + rbeg/rend, then CSR fill (LDS cursors) ------
__global__ __launch_bounds__(1024) void k_degfill(const int* __restrict__ bcnt,
                                                  const int* __restrict__ ebuf,
                                                  float* __restrict__ dinv,
                                                  int* __restrict__ rbeg,
                                                  int* __restrict__ rend,
                                                  int* __restrict__ csr) {
  __shared__ int cnt[BUCK_NODES];
  __shared__ int lcur[BUCK_NODES];
  const int b = blockIdx.x;
  const int t = threadIdx.x;
  if (t < BUCK_NODES) cnt[t] = 0;
  __syncthreads();
  const int beg = b * BCAP, end = beg + bcnt[b];
  for (int j = beg + t; j < end; j += 1024)
    atomicAdd(&cnt[ebuf[j] >> 17], 1);
  __syncthreads();
  int v = (t < BUCK_NODES) ? cnt[t] : 0;
  // Hillis-Steele inclusive scan over 512 (threads >=512 idle but hit barriers)
  for (int off = 1; off < BUCK_NODES; off <<= 1) {
    int u = (t < BUCK_NODES && t >= off) ? cnt[t - off] : 0;
    __syncthreads();
    if (t < BUCK_NODES) cnt[t] += u;
    __syncthreads();
  }
  if (t < BUCK_NODES) {
    const int node = (b << BUCK_SHIFT) + t;
    const int excl = beg + cnt[t] - v;   // start within this bucket's csr range
    lcur[t] = excl;
    if (node < N_NODES) {
      rbeg[node] = excl;
      rend[node] = excl + v;
      dinv[node] = rsqrtf((float)v + 1.0f);   // +1 self-loop
    }
  }
  __syncthreads();
  for (int j = beg + t; j < end; j += 1024) {
    int code = ebuf[j];
    int pos = atomicAdd(&lcur[code >> 17], 1);
    csr[pos] = code & SMASK;
  }
}

// ---------------- Xs = (X @ [P1|P2]) * dinv[i]  ------------------------------
__global__ __launch_bounds__(256) void k_x8(const float* __restrict__ x,
                                            const float* __restrict__ dinv,
                                            const Consts* __restrict__ cst,
                                            float* __restrict__ Xs) {
  __shared__ float xs[32*27];
  const int tid = threadIdx.x;
  const int base = blockIdx.x * 32 * 27;
  for (int j = tid; j < 32*27; j += 256) {
    int g = base + j;
    xs[j] = (g < N_NODES*27) ? x[g] : 0.f;
  }
  __syncthreads();
  int li = tid >> 3, k = tid & 7;
  int node = blockIdx.x * 32 + li;
  if (node < N_NODES) {
    float s = 0.f;
    for (int c = 0; c < 27; ++c) s += xs[li*27+c] * cst->C[c*8+k];
    Xs[node*8+k] = s * dinv[node];
  }
}

// ------ gather pass 1 (float2 lanes): Ys = nd^2(sum+self), dvec --------------
__global__ __launch_bounds__(256) void k_gather1(const int* __restrict__ rbeg,
                                                 const int* __restrict__ rend,
                                                 const int* __restrict__ csr,
                                                 const float* __restrict__ dinv,
                                                 const float2* __restrict__ Xs2,
                                                 float2* __restrict__ Ys2,
                                                 float* __restrict__ dvec) {
  int t = blockIdx.x * 256 + threadIdx.x;
  int d = t >> 2, q = t & 3;
  if (d >= N_NODES) return;
  const int beg = rbeg[d], end = rend[d];
  const float nd = dinv[d];
  float2 self = Xs2[d*4 + q];
  float ax = self.x, ay = self.y;
  float dsum = nd;                  // self-loop contribution
  int j = beg;
  for (; j + 4 <= end; j += 4) {    // unroll-4: independent load batches
    int s0 = csr[j], s1 = csr[j+1], s2 = csr[j+2], s3 = csr[j+3];
    float2 a0 = Xs2[s0*4+q], a1 = Xs2[s1*4+q], a2 = Xs2[s2*4+q], a3 = Xs2[s3*4+q];
    ax += (a0.x + a1.x) + (a2.x + a3.x);
    ay += (a0.y + a1.y) + (a2.y + a3.y);
    if (q == 0) dsum += (dinv[s0] + dinv[s1]) + (dinv[s2] + dinv[s3]);
  }
  for (; j < end; ++j) {
    int s = csr[j];
    float2 a = Xs2[s*4+q];
    ax += a.x; ay += a.y;
    if (q == 0) dsum += dinv[s];
  }
  float nn = nd * nd;
  Ys2[t] = make_float2(nn * ax, nn * ay);   // = n_d * h1 (pre-scaled for pass 2)
  if (q == 0) dvec[d] = nd * dsum;
}

// ------ gather pass 2 (+bank rows): gall = nd(sum+self) + dvec*u + vg --------
__global__ __launch_bounds__(256) void k_gather2g(const int* __restrict__ rbeg,
                                                  const int* __restrict__ rend,
                                                  const int* __restrict__ csr,
                                                  const float* __restrict__ dinv,
                                                  const float2* __restrict__ Ys2,
                                                  const float* __restrict__ dvec,
                                                  const float* __restrict__ bank,
                                                  const Consts* __restrict__ cst,
                                                  float2* __restrict__ gall2) {
  int t = blockIdx.x * 256 + threadIdx.x;
  int d = t >> 2, q = t & 3;
  if (d >= N_NODES + NB_BANK) return;
  int c0 = 2*q, c1 = 2*q + 1;
  if (d >= N_NODES) {               // bank rows
    int bk = d - N_NODES;
    float sx = cst->vb[c0], sy = cst->vb[c1];
    for (int cc = 0; cc < 27; ++cc) {
      float bv = bank[bk*27+cc];
      sx += bv * cst->Rb[cc*8+c0];
      sy += bv * cst->Rb[cc*8+c1];
    }
    gall2[t] = make_float2(sx, sy);
    return;
  }
  const int beg = rbeg[d], end = rend[d];
  float2 self = Ys2[d*4 + q];
  float ax = self.x, ay = self.y;
  int j = beg;
  for (; j + 4 <= end; j += 4) {
    int s0 = csr[j], s1 = csr[j+1], s2 = csr[j+2], s3 = csr[j+3];
    float2 a0 = Ys2[s0*4+q], a1 = Ys2[s1*4+q], a2 = Ys2[s2*4+q], a3 = Ys2[s3*4+q];
    ax += (a0.x + a1.x) + (a2.x + a3.x);
    ay += (a0.y + a1.y) + (a2.y + a3.y);
  }
  for (; j < end; ++j) {
    float2 a = Ys2[csr[j]*4+q];
    ax += a.x; ay += a.y;
  }
  float nd = dinv[d], dv = dvec[d];
  gall2[t] = make_float2(nd * ax + dv * cst->u[c0] + cst->vg[c0],
                         nd * ay + dv * cst->u[c1] + cst->vg[c1]);
}

// ---------------- online-softmax merge helper --------------------------------
__device__ inline void sm_merge(float4& m1, float4& s1,
                                const float4 m2, const float4 s2) {
  float4 M;
  M.x = fmaxf(m1.x, m2.x); M.y = fmaxf(m1.y, m2.y);
  M.z = fmaxf(m1.z, m2.z); M.w = fmaxf(m1.w, m2.w);
  s1.x = s1.x * expf(m1.x - M.x) + s2.x * expf(m2.x - M.x);
  s1.y = s1.y * expf(m1.y - M.y) + s2.y * expf(m2.y - M.y);
  s1.z = s1.z * expf(m1.z - M.z) + s2.z * expf(m2.z - M.z);
  s1.w = s1.w * expf(m1.w - M.w) + s2.w * expf(m2.w - M.w);
  m1 = M;
}

// ---- deterministic z for pair p (recomputed identically in both kernels) ----
__device__ inline float4 compute_z(int p, const int* __restrict__ node1,
                                   const int* __restrict__ node2,
                                   const float* __restrict__ gall) {
  int n1 = node1[p], n2 = node2[p];
  const float4 a = *(const float4*)(gall + (size_t)n1*8);
  const float4 b = *(const float4*)(gall + (size_t)n2*8 + 4);
  return make_float4(a.x+b.x, a.y+b.y, a.z+b.z, a.w+b.w);
}

// ---------------- per-block online (max,sumexp) stats only -------------------
__global__ __launch_bounds__(256) void k_zstats(const int* __restrict__ node1,
                                                const int* __restrict__ node2,
                                                const float* __restrict__ gall,
                                                float4* __restrict__ bs_m,
                                                float4* __restrict__ bs_s) {
  int p = blockIdx.x * 256 + threadIdx.x;
  float4 m = make_float4(-1e30f, -1e30f, -1e30f, -1e30f);
  float4 s = make_float4(0.f, 0.f, 0.f, 0.f);
  if (p < N_PAIRS) {
    m = compute_z(p, node1, node2, gall);
    s = make_float4(1.f, 1.f, 1.f, 1.f);
  }
  __shared__ float4 lm[256], ls[256];
  lm[threadIdx.x] = m; ls[threadIdx.x] = s;
  __syncthreads();
  for (int st = 128; st > 0; st >>= 1) {
    if (threadIdx.x < st) {
      float4 mm = lm[threadIdx.x], ss = ls[threadIdx.x];
      sm_merge(mm, ss, lm[threadIdx.x + st], ls[threadIdx.x + st]);
      lm[threadIdx.x] = mm; ls[threadIdx.x] = ss;
    }
    __syncthreads();
  }
  if (threadIdx.x == 0) { bs_m[blockIdx.x] = lm[0]; bs_s[blockIdx.x] = ls[0]; }
}

// ---- final: per-block redundant combine of stats + recompute z + write ------
__global__ __launch_bounds__(256) void k_final(const int* __restrict__ node1,
                                               const int* __restrict__ node2,
                                               const float* __restrict__ gall,
                                               const float4* __restrict__ bs_m,
                                               const float4* __restrict__ bs_s,
                                               float* __restrict__ out) {
  float4 m = make_float4(-1e30f, -1e30f, -1e30f, -1e30f);
  float4 s = make_float4(0.f, 0.f, 0.f, 0.f);
  for (int i = threadIdx.x; i < NZBLK; i += 256)
    sm_merge(m, s, bs_m[i], bs_s[i]);
  __shared__ float4 lm[256], ls[256];
  lm[threadIdx.x] = m; ls[threadIdx.x] = s;
  __syncthreads();
  for (int st = 128; st > 0; st >>= 1) {
    if (threadIdx.x < st) {
      float4 mm = lm[threadIdx.x], ss = ls[threadIdx.x];
      sm_merge(mm, ss, lm[threadIdx.x + st], ls[threadIdx.x + st]);
      lm[threadIdx.x] = mm; ls[threadIdx.x] = ss;
    }
    __syncthreads();
  }
  const float4 M = lm[0], S = ls[0];
  int p = blockIdx.x * 256 + threadIdx.x;
  if (p < N_PAIRS) {
    float4 zv = compute_z(p, node1, node2, gall);
    float4 o = make_float4(expf(zv.x - M.x) / S.x, expf(zv.y - M.y) / S.y,
                           expf(zv.z - M.z) / S.z, expf(zv.w - M.w) / S.w);
    ((float4*)out)[p] = o;
  }
}

extern "C" void kernel_launch(void* const* d_in, const int* in_sizes, int n_in,
                              void* d_out, int out_size, void* d_ws, size_t ws_size,
                              hipStream_t stream) {
  const float* x    = (const float*)d_in[0];
  const float* bank = (const float*)d_in[1];
  const float* W1   = (const float*)d_in[2];
  const float* b1   = (const float*)d_in[3];
  const float* W2   = (const float*)d_in[4];
  const float* b2   = (const float*)d_in[5];
  const float* Wb   = (const float*)d_in[6];
  const float* bb   = (const float*)d_in[7];
  const float* Wf1  = (const float*)d_in[8];
  const float* bf1  = (const float*)d_in[9];
  const float* Wf2  = (const float*)d_in[10];
  const float* bf2  = (const float*)d_in[11];
  const float* Wf3  = (const float*)d_in[12];
  const float* bf3  = (const float*)d_in[13];
  const int* ei     = (const int*)d_in[14];
  const int* node1  = (const int*)d_in[15];
  const int* node2  = (const int*)d_in[16];
  float* out = (float*)d_out;

  char* w = (char*)d_ws;
  size_t off = 0;
  auto take = [&](size_t bytes) -> char* {
    char* p = w + off;
    off = (off + bytes + 255) & ~(size_t)255;
    return p;
  };
  Consts* cst    = (Consts*)take(sizeof(Consts));
  int*    bcnt   = (int*)take(NBUCK * 4);
  float*  dinv   = (float*)take(N_NODES * 4);
  int*    rbeg   = (int*)take(N_NODES * 4);
  int*    rend   = (int*)take(N_NODES * 4);
  int*    csr    = (int*)take((size_t)NBUCK * BCAP * 4);
  float*  Xs     = (float*)take((size_t)N_NODES * 8 * 4);
  float*  Ys     = (float*)take((size_t)N_NODES * 8 * 4);
  float*  dvec   = (float*)take(N_NODES * 4);
  float*  gall   = (float*)take((size_t)(N_NODES + NB_BANK) * 8 * 4);
  int*    ebuf   = (int*)take((size_t)NBUCK * BCAP * 4);
  float4* bs_m   = (float4*)take((size_t)NZBLK * 16);
  float4* bs_s   = (float4*)take((size_t)NZBLK * 16);

  hipMemsetAsync(bcnt, 0, NBUCK * 4, stream);

  // single-pass bucket scatter + (extra block) weight-chain precompute
  k_scatter<<<NSCAT + 1, 1024, 0, stream>>>(ei, bcnt, ebuf, W1, b1, W2, b2,
                                            Wb, bb, Wf1, bf1, Wf2, bf2,
                                            Wf3, bf3, cst);
  // per-bucket: degree/dinv/rbeg/rend + CSR fill (1024 thr: 8 iters/stream)
  k_degfill<<<NBUCK, 1024, 0, stream>>>(bcnt, ebuf, dinv, rbeg, rend, csr);
  // features
  k_x8<<<(N_NODES + 31) / 32, 256, 0, stream>>>(x, dinv, cst, Xs);
  // propagation (atomic-free float2 gathers, unroll-4)
  k_gather1<<<(N_NODES * 4 + 255) / 256, 256, 0, stream>>>(
      rbeg, rend, csr, dinv, (const float2*)Xs, (float2*)Ys, dvec);
  k_gather2g<<<((N_NODES + NB_BANK) * 4 + 255) / 256, 256, 0, stream>>>(
      rbeg, rend, csr, dinv, (const float2*)Ys, dvec, bank, cst, (float2*)gall);
  // pair phase: stats then recompute+normalize (no z materialization)
  k_zstats<<<NZBLK, 256, 0, stream>>>(node1, node2, gall, bs_m, bs_s);
  k_final<<<NZBLK, 256, 0, stream>>>(node1, node2, gall, bs_m, bs_s, out);
}

// Round 10
// 204.178 us; speedup vs baseline: 1.0743x; 1.0743x over previous
//
#include <hip/hip_runtime.h>
#include <math.h>

#define N_NODES 100000
#define N_EDGES 1600000
#define NB_BANK 1000
#define N_PAIRS 500000

#define BUCK_SHIFT 9
#define BUCK_NODES 512
#define NBUCK 196            // ceil(N_NODES/512)
#define BCAP 10240           // fixed ebuf/csr stride per bucket (mean 8163 + 22 sigma)
#define EPB 4096             // edges per scatter block (392 blocks: 1.5/CU)
#define NSCAT 391            // ceil(N_EDGES/EPB)
#define NZBLK 1954           // ceil(N_PAIRS/256)
#define SMASK 0x1FFFF        // low 17 bits = src id (N_NODES < 2^17)

struct Consts {
  float C[27*8];    // [P1|P2] : X -> 8 channels
  float Rb[27*8];   // [Wb@Ttop | Wb@Tbot]
  float u[8];       // coefficient of dvec (A-hat * 1)
  float vg[8];      // graph-row constant
  float vb[8];      // bank-row constant
};

// ---- dense weight-chain precompute, runs as the extra block of k_scatter ----
__device__ void precompute_body(
    const float* __restrict__ W1, const float* __restrict__ b1,
    const float* __restrict__ W2, const float* __restrict__ b2,
    const float* __restrict__ Wb, const float* __restrict__ bb,
    const float* __restrict__ Wf1, const float* __restrict__ bf1,
    const float* __restrict__ Wf2, const float* __restrict__ bf2,
    const float* __restrict__ Wf3, const float* __restrict__ bf3,
    Consts* __restrict__ cst) {
  __shared__ float A[40*4];    // Wf2 @ Wf3
  __shared__ float T[100*4];   // Wf1 @ A
  __shared__ float B[60*8];    // W2 @ [Ttop|Tbot]
  __shared__ float cvec[4];
  const int tid = threadIdx.x;
  const int nt = blockDim.x;

  for (int idx = tid; idx < 160; idx += nt) {
    int r = idx >> 2, k = idx & 3;
    float s = 0.f;
    for (int j = 0; j < 20; ++j) s += Wf2[r*20+j] * Wf3[j*4+k];
    A[idx] = s;
  }
  __syncthreads();
  for (int idx = tid; idx < 400; idx += nt) {
    int r = idx >> 2, k = idx & 3;
    float s = 0.f;
    for (int j = 0; j < 40; ++j) s += Wf1[r*40+j] * A[j*4+k];
    T[idx] = s;
  }
  if (tid < 4) {
    float s = bf3[tid];
    for (int j = 0; j < 40; ++j) s += bf1[j] * A[j*4+tid];
    for (int j = 0; j < 20; ++j) s += bf2[j] * Wf3[j*4+tid];
    cvec[tid] = s;
  }
  __syncthreads();
  for (int idx = tid; idx < 480; idx += nt) {
    int r = idx >> 3, k = idx & 7;
    int half = k >> 2, kk = k & 3;
    float s = 0.f;
    for (int j = 0; j < 50; ++j) s += W2[r*50+j] * T[(half*50+j)*4+kk];
    B[idx] = s;
  }
  __syncthreads();
  for (int idx = tid; idx < 456; idx += nt) {
    if (idx < 216) {                       // C = W1 @ B [27,8]
      int r = idx >> 3, k = idx & 7;
      float s = 0.f;
      for (int j = 0; j < 60; ++j) s += W1[r*60+j] * B[j*8+k];
      cst->C[idx] = s;
    } else if (idx < 432) {                // Rb = Wb @ [Ttop|Tbot] [27,8]
      int i2 = idx - 216;
      int r = i2 >> 3, k = i2 & 7, half = k >> 2, kk = k & 3;
      float s = 0.f;
      for (int j = 0; j < 50; ++j) s += Wb[r*50+j] * T[(half*50+j)*4+kk];
      cst->Rb[i2] = s;
    } else if (idx < 440) {                // u = b1 @ B
      int k = idx - 432;
      float s = 0.f;
      for (int j = 0; j < 60; ++j) s += b1[j] * B[j*8+k];
      cst->u[k] = s;
    } else if (idx < 448) {                // vg = b2 @ [Ttop|Tbot] (+c on half 0)
      int k = idx - 440, half = k >> 2, kk = k & 3;
      float s = (half == 0) ? cvec[kk] : 0.f;
      for (int j = 0; j < 50; ++j) s += b2[j] * T[(half*50+j)*4+kk];
      cst->vg[k] = s;
    } else {                               // vb = bb @ [Ttop|Tbot] (+c on half 0)
      int k = idx - 448, half = k >> 2, kk = k & 3;
      float s = (half == 0) ? cvec[kk] : 0.f;
      for (int j = 0; j < 50; ++j) s += bb[j] * T[(half*50+j)*4+kk];
      cst->vb[k] = s;
    }
  }
}

// --- single-pass bucket scatter into fixed-stride ebuf; bcnt[b] -> counts ----
// dst ids register-cached across the two passes; extra block runs precompute.
__global__ __launch_bounds__(1024) void k_scatter(
    const int* __restrict__ ei, int* __restrict__ bcnt, int* __restrict__ ebuf,
    const float* __restrict__ W1, const float* __restrict__ b1,
    const float* __restrict__ W2, const float* __restrict__ b2,
    const float* __restrict__ Wb, const float* __restrict__ bb,
    const float* __restrict__ Wf1, const float* __restrict__ bf1,
    const float* __restrict__ Wf2, const float* __restrict__ bf2,
    const float* __restrict__ Wf3, const float* __restrict__ bf3,
    Consts* __restrict__ cst) {
  if (blockIdx.x == NSCAT) {   // whole-block branch: safe with __syncthreads
    precompute_body(W1, b1, W2, b2, Wb, bb, Wf1, bf1, Wf2, bf2, Wf3, bf3, cst);
    return;
  }
  __shared__ int hist[NBUCK];
  __shared__ int base[NBUCK];
  const int t = threadIdx.x;
  const int e0 = blockIdx.x * EPB;
  int dcache[EPB / 1024];
  if (t < NBUCK) hist[t] = 0;
  __syncthreads();
#pragma unroll
  for (int i = 0; i < EPB / 1024; ++i) {
    int e = e0 + i * 1024 + t;
    int d = (e < N_EDGES) ? ei[N_EDGES + e] : -1;
    dcache[i] = d;
    if (d >= 0) atomicAdd(&hist[d >> BUCK_SHIFT], 1);
  }
  __syncthreads();
  if (t < NBUCK) {
    int h = hist[t];
    base[t] = h ? (t * BCAP + atomicAdd(&bcnt[t], h)) : 0;
    hist[t] = 0;
  }
  __syncthreads();
#pragma unroll
  for (int i = 0; i < EPB / 1024; ++i) {
    int e = e0 + i * 1024 + t;
    int d = dcache[i];
    if (d >= 0) {
      int s = ei[e];
      int b = d >> BUCK_SHIFT;
      int pos = base[b] + atomicAdd(&hist[b], 1);
      ebuf[pos] = ((d & (BUCK_NODES - 1)) << 17) | s;
    }
  }
}

// -- per-bucket: degree -> dinv + rbeg/rend, then CSR fill (LDS cursors) ------
__global__ __launch_bounds__(1024) void k_degfill(const int* __restrict__ bcnt,
                                                  const int* __restrict__ ebuf,
                                                  float* __restrict__ dinv,
                                                  int* __restrict__ rbeg,
                                                  int* __restrict__ rend,
                                                  int* __restrict__ csr) {
  __shared__ int cnt[BUCK_NODES];
  __shared__ int lcur[BUCK_NODES];
  const int b = blockIdx.x;
  const int t = threadIdx.x;
  if (t < BUCK_NODES) cnt[t] = 0;
  __syncthreads();
  const int beg = b * BCAP, end = beg + bcnt[b];
  for (int j = beg + t; j < end; j += 1024)
    atomicAdd(&cnt[ebuf[j] >> 17], 1);
  __syncthreads();
  int v = (t < BUCK_NODES) ? cnt[t] : 0;
  // Hillis-Steele inclusive scan over 512 (threads >=512 idle but hit barriers)
  for (int off = 1; off < BUCK_NODES; off <<= 1) {
    int u = (t < BUCK_NODES && t >= off) ? cnt[t - off] : 0;
    __syncthreads();
    if (t < BUCK_NODES) cnt[t] += u;
    __syncthreads();
  }
  if (t < BUCK_NODES) {
    const int node = (b << BUCK_SHIFT) + t;
    const int excl = beg + cnt[t] - v;   // start within this bucket's csr range
    lcur[t] = excl;
    if (node < N_NODES) {
      rbeg[node] = excl;
      rend[node] = excl + v;
      dinv[node] = rsqrtf((float)v + 1.0f);   // +1 self-loop
    }
  }
  __syncthreads();
  for (int j = beg + t; j < end; j += 1024) {
    int code = ebuf[j];
    int pos = atomicAdd(&lcur[code >> 17], 1);
    csr[pos] = code & SMASK;
  }
}

// ---------------- Xs = (X @ [P1|P2]) * dinv[i]  ------------------------------
__global__ __launch_bounds__(256) void k_x8(const float* __restrict__ x,
                                            const float* __restrict__ dinv,
                                            const Consts* __restrict__ cst,
                                            float* __restrict__ Xs) {
  __shared__ float xs[32*27];
  const int tid = threadIdx.x;
  const int base = blockIdx.x * 32 * 27;
  for (int j = tid; j < 32*27; j += 256) {
    int g = base + j;
    xs[j] = (g < N_NODES*27) ? x[g] : 0.f;
  }
  __syncthreads();
  int li = tid >> 3, k = tid & 7;
  int node = blockIdx.x * 32 + li;
  if (node < N_NODES) {
    float s = 0.f;
    for (int c = 0; c < 27; ++c) s += xs[li*27+c] * cst->C[c*8+k];
    Xs[node*8+k] = s * dinv[node];
  }
}

// ------ gather pass 1 (float2 lanes, unroll-8): Ys = nd^2(sum+self), dvec ----
__global__ __launch_bounds__(256) void k_gather1(const int* __restrict__ rbeg,
                                                 const int* __restrict__ rend,
                                                 const int* __restrict__ csr,
                                                 const float* __restrict__ dinv,
                                                 const float2* __restrict__ Xs2,
                                                 float2* __restrict__ Ys2,
                                                 float* __restrict__ dvec) {
  int t = blockIdx.x * 256 + threadIdx.x;
  int d = t >> 2, q = t & 3;
  if (d >= N_NODES) return;
  const int beg = rbeg[d], end = rend[d];
  const float nd = dinv[d];
  float2 self = Xs2[d*4 + q];
  float ax = self.x, ay = self.y;
  float dsum = nd;                  // self-loop contribution
  int j = beg;
  for (; j + 8 <= end; j += 8) {    // unroll-8: 8 independent loads in flight
    int s0 = csr[j],   s1 = csr[j+1], s2 = csr[j+2], s3 = csr[j+3];
    int s4 = csr[j+4], s5 = csr[j+5], s6 = csr[j+6], s7 = csr[j+7];
    float2 a0 = Xs2[s0*4+q], a1 = Xs2[s1*4+q], a2 = Xs2[s2*4+q], a3 = Xs2[s3*4+q];
    float2 a4 = Xs2[s4*4+q], a5 = Xs2[s5*4+q], a6 = Xs2[s6*4+q], a7 = Xs2[s7*4+q];
    ax += ((a0.x + a1.x) + (a2.x + a3.x)) + ((a4.x + a5.x) + (a6.x + a7.x));
    ay += ((a0.y + a1.y) + (a2.y + a3.y)) + ((a4.y + a5.y) + (a6.y + a7.y));
    if (q == 0)
      dsum += ((dinv[s0] + dinv[s1]) + (dinv[s2] + dinv[s3]))
            + ((dinv[s4] + dinv[s5]) + (dinv[s6] + dinv[s7]));
  }
  for (; j < end; ++j) {
    int s = csr[j];
    float2 a = Xs2[s*4+q];
    ax += a.x; ay += a.y;
    if (q == 0) dsum += dinv[s];
  }
  float nn = nd * nd;
  Ys2[t] = make_float2(nn * ax, nn * ay);   // = n_d * h1 (pre-scaled for pass 2)
  if (q == 0) dvec[d] = nd * dsum;
}

// ------ gather pass 2 (+bank rows): gall = nd(sum+self) + dvec*u + vg --------
__global__ __launch_bounds__(256) void k_gather2g(const int* __restrict__ rbeg,
                                                  const int* __restrict__ rend,
                                                  const int* __restrict__ csr,
                                                  const float* __restrict__ dinv,
                                                  const float2* __restrict__ Ys2,
                                                  const float* __restrict__ dvec,
                                                  const float* __restrict__ bank,
                                                  const Consts* __restrict__ cst,
                                                  float2* __restrict__ gall2) {
  int t = blockIdx.x * 256 + threadIdx.x;
  int d = t >> 2, q = t & 3;
  if (d >= N_NODES + NB_BANK) return;
  int c0 = 2*q, c1 = 2*q + 1;
  if (d >= N_NODES) {               // bank rows
    int bk = d - N_NODES;
    float sx = cst->vb[c0], sy = cst->vb[c1];
    for (int cc = 0; cc < 27; ++cc) {
      float bv = bank[bk*27+cc];
      sx += bv * cst->Rb[cc*8+c0];
      sy += bv * cst->Rb[cc*8+c1];
    }
    gall2[t] = make_float2(sx, sy);
    return;
  }
  const int beg = rbeg[d], end = rend[d];
  float2 self = Ys2[d*4 + q];
  float ax = self.x, ay = self.y;
  int j = beg;
  for (; j + 8 <= end; j += 8) {
    int s0 = csr[j],   s1 = csr[j+1], s2 = csr[j+2], s3 = csr[j+3];
    int s4 = csr[j+4], s5 = csr[j+5], s6 = csr[j+6], s7 = csr[j+7];
    float2 a0 = Ys2[s0*4+q], a1 = Ys2[s1*4+q], a2 = Ys2[s2*4+q], a3 = Ys2[s3*4+q];
    float2 a4 = Ys2[s4*4+q], a5 = Ys2[s5*4+q], a6 = Ys2[s6*4+q], a7 = Ys2[s7*4+q];
    ax += ((a0.x + a1.x) + (a2.x + a3.x)) + ((a4.x + a5.x) + (a6.x + a7.x));
    ay += ((a0.y + a1.y) + (a2.y + a3.y)) + ((a4.y + a5.y) + (a6.y + a7.y));
  }
  for (; j < end; ++j) {
    float2 a = Ys2[csr[j]*4+q];
    ax += a.x; ay += a.y;
  }
  float nd = dinv[d], dv = dvec[d];
  gall2[t] = make_float2(nd * ax + dv * cst->u[c0] + cst->vg[c0],
                         nd * ay + dv * cst->u[c1] + cst->vg[c1]);
}

// ---------------- online-softmax merge helper --------------------------------
__device__ inline void sm_merge(float4& m1, float4& s1,
                                const float4 m2, const float4 s2) {
  float4 M;
  M.x = fmaxf(m1.x, m2.x); M.y = fmaxf(m1.y, m2.y);
  M.z = fmaxf(m1.z, m2.z); M.w = fmaxf(m1.w, m2.w);
  s1.x = s1.x * expf(m1.x - M.x) + s2.x * expf(m2.x - M.x);
  s1.y = s1.y * expf(m1.y - M.y) + s2.y * expf(m2.y - M.y);
  s1.z = s1.z * expf(m1.z - M.z) + s2.z * expf(m2.z - M.z);
  s1.w = s1.w * expf(m1.w - M.w) + s2.w * expf(m2.w - M.w);
  m1 = M;
}

// ---------------- pair gather + z + per-block online (max,sumexp) ------------
__global__ __launch_bounds__(256) void k_z(const int* __restrict__ node1,
                                           const int* __restrict__ node2,
                                           const float* __restrict__ gall,
                                           float* __restrict__ z,
                                           float4* __restrict__ bs_m,
                                           float4* __restrict__ bs_s) {
  int p = blockIdx.x * 256 + threadIdx.x;
  float4 m = make_float4(-1e30f, -1e30f, -1e30f, -1e30f);
  float4 s = make_float4(0.f, 0.f, 0.f, 0.f);
  if (p < N_PAIRS) {
    int n1 = node1[p], n2 = node2[p];
    const float4 a = *(const float4*)(gall + (size_t)n1*8);
    const float4 b = *(const float4*)(gall + (size_t)n2*8 + 4);
    float4 zv = make_float4(a.x+b.x, a.y+b.y, a.z+b.z, a.w+b.w);
    ((float4*)z)[p] = zv;
    m = zv; s = make_float4(1.f, 1.f, 1.f, 1.f);
  }
  __shared__ float4 lm[256], ls[256];
  lm[threadIdx.x] = m; ls[threadIdx.x] = s;
  __syncthreads();
  for (int st = 128; st > 0; st >>= 1) {
    if (threadIdx.x < st) {
      float4 mm = lm[threadIdx.x], ss = ls[threadIdx.x];
      sm_merge(mm, ss, lm[threadIdx.x + st], ls[threadIdx.x + st]);
      lm[threadIdx.x] = mm; ls[threadIdx.x] = ss;
    }
    __syncthreads();
  }
  if (threadIdx.x == 0) { bs_m[blockIdx.x] = lm[0]; bs_s[blockIdx.x] = ls[0]; }
}

// ---------------- combine block stats -> global (m, S) -----------------------
__global__ __launch_bounds__(256) void k_comb(const float4* __restrict__ bs_m,
                                              const float4* __restrict__ bs_s,
                                              float* __restrict__ gms) {
  float4 m = make_float4(-1e30f, -1e30f, -1e30f, -1e30f);
  float4 s = make_float4(0.f, 0.f, 0.f, 0.f);
  for (int i = threadIdx.x; i < NZBLK; i += 256)
    sm_merge(m, s, bs_m[i], bs_s[i]);
  __shared__ float4 lm[256], ls[256];
  lm[threadIdx.x] = m; ls[threadIdx.x] = s;
  __syncthreads();
  for (int st = 128; st > 0; st >>= 1) {
    if (threadIdx.x < st) {
      float4 mm = lm[threadIdx.x], ss = ls[threadIdx.x];
      sm_merge(mm, ss, lm[threadIdx.x + st], ls[threadIdx.x + st]);
      lm[threadIdx.x] = mm; ls[threadIdx.x] = ss;
    }
    __syncthreads();
  }
  if (threadIdx.x == 0) {
    float4 M = lm[0], S = ls[0];
    gms[0] = M.x; gms[1] = M.y; gms[2] = M.z; gms[3] = M.w;
    gms[4] = S.x; gms[5] = S.y; gms[6] = S.z; gms[7] = S.w;
  }
}

// ---------------- normalize --------------------------------------------------
__global__ __launch_bounds__(256) void k_final(const float* __restrict__ z,
                                               const float* __restrict__ gms,
                                               float* __restrict__ out) {
  int p = blockIdx.x * 256 + threadIdx.x;
  if (p < N_PAIRS) {
    float m0 = gms[0], m1 = gms[1], m2 = gms[2], m3 = gms[3];
    float i0 = 1.f / gms[4], i1 = 1.f / gms[5];
    float i2 = 1.f / gms[6], i3 = 1.f / gms[7];
    float4 zv = ((const float4*)z)[p];
    float4 o = make_float4(expf(zv.x - m0) * i0, expf(zv.y - m1) * i1,
                           expf(zv.z - m2) * i2, expf(zv.w - m3) * i3);
    ((float4*)out)[p] = o;
  }
}

extern "C" void kernel_launch(void* const* d_in, const int* in_sizes, int n_in,
                              void* d_out, int out_size, void* d_ws, size_t ws_size,
                              hipStream_t stream) {
  const float* x    = (const float*)d_in[0];
  const float* bank = (const float*)d_in[1];
  const float* W1   = (const float*)d_in[2];
  const float* b1   = (const float*)d_in[3];
  const float* W2   = (const float*)d_in[4];
  const float* b2   = (const float*)d_in[5];
  const float* Wb   = (const float*)d_in[6];
  const float* bb   = (const float*)d_in[7];
  const float* Wf1  = (const float*)d_in[8];
  const float* bf1  = (const float*)d_in[9];
  const float* Wf2  = (const float*)d_in[10];
  const float* bf2  = (const float*)d_in[11];
  const float* Wf3  = (const float*)d_in[12];
  const float* bf3  = (const float*)d_in[13];
  const int* ei     = (const int*)d_in[14];
  const int* node1  = (const int*)d_in[15];
  const int* node2  = (const int*)d_in[16];
  float* out = (float*)d_out;

  char* w = (char*)d_ws;
  size_t off = 0;
  auto take = [&](size_t bytes) -> char* {
    char* p = w + off;
    off = (off + bytes + 255) & ~(size_t)255;
    return p;
  };
  Consts* cst    = (Consts*)take(sizeof(Consts));
  int*    bcnt   = (int*)take(NBUCK * 4);
  float*  dinv   = (float*)take(N_NODES * 4);
  int*    rbeg   = (int*)take(N_NODES * 4);
  int*    rend   = (int*)take(N_NODES * 4);
  int*    csr    = (int*)take((size_t)NBUCK * BCAP * 4);
  float*  Xs     = (float*)take((size_t)N_NODES * 8 * 4);
  float*  Ys     = (float*)take((size_t)N_NODES * 8 * 4);
  float*  dvec   = (float*)take(N_NODES * 4);
  float*  gall   = (float*)take((size_t)(N_NODES + NB_BANK) * 8 * 4);
  // ebuf (build phase) and z (pair phase) have disjoint lifetimes -> share.
  char*   shreg  = take((size_t)NBUCK * BCAP * 4 > (size_t)N_PAIRS * 16
                        ? (size_t)NBUCK * BCAP * 4 : (size_t)N_PAIRS * 16);
  int*    ebuf   = (int*)shreg;
  float*  z      = (float*)shreg;
  float4* bs_m   = (float4*)take((size_t)NZBLK * 16);
  float4* bs_s   = (float4*)take((size_t)NZBLK * 16);
  float*  gms    = (float*)take(32);

  hipMemsetAsync(bcnt, 0, NBUCK * 4, stream);

  // single-pass bucket scatter + (extra block) weight-chain precompute
  k_scatter<<<NSCAT + 1, 1024, 0, stream>>>(ei, bcnt, ebuf, W1, b1, W2, b2,
                                            Wb, bb, Wf1, bf1, Wf2, bf2,
                                            Wf3, bf3, cst);
  // per-bucket: degree/dinv/rbeg/rend + CSR fill
  k_degfill<<<NBUCK, 1024, 0, stream>>>(bcnt, ebuf, dinv, rbeg, rend, csr);
  // features
  k_x8<<<(N_NODES + 31) / 32, 256, 0, stream>>>(x, dinv, cst, Xs);
  // propagation (atomic-free float2 gathers, unroll-8)
  k_gather1<<<(N_NODES * 4 + 255) / 256, 256, 0, stream>>>(
      rbeg, rend, csr, dinv, (const float2*)Xs, (float2*)Ys, dvec);
  k_gather2g<<<((N_NODES + NB_BANK) * 4 + 255) / 256, 256, 0, stream>>>(
      rbeg, rend, csr, dinv, (const float2*)Ys, dvec, bank, cst, (float2*)gall);
  // pair phase: z + block stats, single-block combine, normalize
  k_z<<<NZBLK, 256, 0, stream>>>(node1, node2, gall, z, bs_m, bs_s);
  k_comb<<<1, 256, 0, stream>>>(bs_m, bs_s, gms);
  k_final<<<NZBLK, 256, 0, stream>>>(z, gms, out);
}

// Round 12
// 202.102 us; speedup vs baseline: 1.0853x; 1.0103x over previous
//
#include <hip/hip_runtime.h>
#include <math.h>

#define N_NODES 100000
#define N_EDGES 1600000
#define NB_BANK 1000
#define N_PAIRS 500000

#define BUCK_SHIFT 9
#define BUCK_NODES 512
#define NBUCK 196            // ceil(N_NODES/512)
#define BCAP 10240           // fixed ebuf/csr stride per bucket (mean 8163 + 22 sigma)
#define EPB 4096             // edges per scatter block (392 blocks: 1.5/CU)
#define NSCAT 391            // ceil(N_EDGES/EPB)
#define NZBLK 1954           // ceil(N_PAIRS/256)
#define SMASK 0x1FFFF        // low 17 bits = src id (N_NODES < 2^17)

struct Consts {
  float C[27*8];    // [P1|P2] : X -> 8 channels
  float Rb[27*8];   // [Wb@Ttop | Wb@Tbot]
  float u[8];       // coefficient of dvec (A-hat * 1)
  float vg[8];      // graph-row constant
  float vb[8];      // bank-row constant
};

// ---- dense weight-chain precompute, runs as the extra block of k_scatter ----
__device__ void precompute_body(
    const float* __restrict__ W1, const float* __restrict__ b1,
    const float* __restrict__ W2, const float* __restrict__ b2,
    const float* __restrict__ Wb, const float* __restrict__ bb,
    const float* __restrict__ Wf1, const float* __restrict__ bf1,
    const float* __restrict__ Wf2, const float* __restrict__ bf2,
    const float* __restrict__ Wf3, const float* __restrict__ bf3,
    Consts* __restrict__ cst) {
  __shared__ float A[40*4];    // Wf2 @ Wf3
  __shared__ float T[100*4];   // Wf1 @ A
  __shared__ float B[60*8];    // W2 @ [Ttop|Tbot]
  __shared__ float cvec[4];
  const int tid = threadIdx.x;
  const int nt = blockDim.x;

  for (int idx = tid; idx < 160; idx += nt) {
    int r = idx >> 2, k = idx & 3;
    float s = 0.f;
    for (int j = 0; j < 20; ++j) s += Wf2[r*20+j] * Wf3[j*4+k];
    A[idx] = s;
  }
  __syncthreads();
  for (int idx = tid; idx < 400; idx += nt) {
    int r = idx >> 2, k = idx & 3;
    float s = 0.f;
    for (int j = 0; j < 40; ++j) s += Wf1[r*40+j] * A[j*4+k];
    T[idx] = s;
  }
  if (tid < 4) {
    float s = bf3[tid];
    for (int j = 0; j < 40; ++j) s += bf1[j] * A[j*4+tid];
    for (int j = 0; j < 20; ++j) s += bf2[j] * Wf3[j*4+tid];
    cvec[tid] = s;
  }
  __syncthreads();
  for (int idx = tid; idx < 480; idx += nt) {
    int r = idx >> 3, k = idx & 7;
    int half = k >> 2, kk = k & 3;
    float s = 0.f;
    for (int j = 0; j < 50; ++j) s += W2[r*50+j] * T[(half*50+j)*4+kk];
    B[idx] = s;
  }
  __syncthreads();
  for (int idx = tid; idx < 456; idx += nt) {
    if (idx < 216) {                       // C = W1 @ B [27,8]
      int r = idx >> 3, k = idx & 7;
      float s = 0.f;
      for (int j = 0; j < 60; ++j) s += W1[r*60+j] * B[j*8+k];
      cst->C[idx] = s;
    } else if (idx < 432) {                // Rb = Wb @ [Ttop|Tbot] [27,8]
      int i2 = idx - 216;
      int r = i2 >> 3, k = i2 & 7, half = k >> 2, kk = k & 3;
      float s = 0.f;
      for (int j = 0; j < 50; ++j) s += Wb[r*50+j] * T[(half*50+j)*4+kk];
      cst->Rb[i2] = s;
    } else if (idx < 440) {                // u = b1 @ B
      int k = idx - 432;
      float s = 0.f;
      for (int j = 0; j < 60; ++j) s += b1[j] * B[j*8+k];
      cst->u[k] = s;
    } else if (idx < 448) {                // vg = b2 @ [Ttop|Tbot] (+c on half 0)
      int k = idx - 440, half = k >> 2, kk = k & 3;
      float s = (half == 0) ? cvec[kk] : 0.f;
      for (int j = 0; j < 50; ++j) s += b2[j] * T[(half*50+j)*4+kk];
      cst->vg[k] = s;
    } else {                               // vb = bb @ [Ttop|Tbot] (+c on half 0)
      int k = idx - 448, half = k >> 2, kk = k & 3;
      float s = (half == 0) ? cvec[kk] : 0.f;
      for (int j = 0; j < 50; ++j) s += bb[j] * T[(half*50+j)*4+kk];
      cst->vb[k] = s;
    }
  }
}

// --- single-pass bucket scatter into fixed-stride ebuf; bcnt[b] -> counts ----
// dst ids register-cached across the two passes; extra block runs precompute.
__global__ __launch_bounds__(1024) void k_scatter(
    const int* __restrict__ ei, int* __restrict__ bcnt, int* __restrict__ ebuf,
    const float* __restrict__ W1, const float* __restrict__ b1,
    const float* __restrict__ W2, const float* __restrict__ b2,
    const float* __restrict__ Wb, const float* __restrict__ bb,
    const float* __restrict__ Wf1, const float* __restrict__ bf1,
    const float* __restrict__ Wf2, const float* __restrict__ bf2,
    const float* __restrict__ Wf3, const float* __restrict__ bf3,
    Consts* __restrict__ cst) {
  if (blockIdx.x == NSCAT) {   // whole-block branch: safe with __syncthreads
    precompute_body(W1, b1, W2, b2, Wb, bb, Wf1, bf1, Wf2, bf2, Wf3, bf3, cst);
    return;
  }
  __shared__ int hist[NBUCK];
  __shared__ int base[NBUCK];
  const int t = threadIdx.x;
  const int e0 = blockIdx.x * EPB;
  int dcache[EPB / 1024];
  if (t < NBUCK) hist[t] = 0;
  __syncthreads();
#pragma unroll
  for (int i = 0; i < EPB / 1024; ++i) {
    int e = e0 + i * 1024 + t;
    int d = (e < N_EDGES) ? ei[N_EDGES + e] : -1;
    dcache[i] = d;
    if (d >= 0) atomicAdd(&hist[d >> BUCK_SHIFT], 1);
  }
  __syncthreads();
  if (t < NBUCK) {
    int h = hist[t];
    base[t] = h ? (t * BCAP + atomicAdd(&bcnt[t], h)) : 0;
    hist[t] = 0;
  }
  __syncthreads();
#pragma unroll
  for (int i = 0; i < EPB / 1024; ++i) {
    int e = e0 + i * 1024 + t;
    int d = dcache[i];
    if (d >= 0) {
      int s = ei[e];
      int b = d >> BUCK_SHIFT;
      int pos = base[b] + atomicAdd(&hist[b], 1);
      ebuf[pos] = ((d & (BUCK_NODES - 1)) << 17) | s;
    }
  }
}

// -- per-bucket: degree -> dinv + rbeg/rend, then CSR fill (LDS cursors) ------
__global__ __launch_bounds__(1024) void k_degfill(const int* __restrict__ bcnt,
                                                  const int* __restrict__ ebuf,
                                                  float* __restrict__ dinv,
                                                  int* __restrict__ rbeg,
                                                  int* __restrict__ rend,
                                                  int* __restrict__ csr) {
  __shared__ int cnt[BUCK_NODES];
  __shared__ int lcur[BUCK_NODES];
  const int b = blockIdx.x;
  const int t = threadIdx.x;
  if (t < BUCK_NODES) cnt[t] = 0;
  __syncthreads();
  const int beg = b * BCAP, end = beg + bcnt[b];
  for (int j = beg + t; j < end; j += 1024)
    atomicAdd(&cnt[ebuf[j] >> 17], 1);
  __syncthreads();
  int v = (t < BUCK_NODES) ? cnt[t] : 0;
  // Hillis-Steele inclusive scan over 512 (threads >=512 idle but hit barriers)
  for (int off = 1; off < BUCK_NODES; off <<= 1) {
    int u = (t < BUCK_NODES && t >= off) ? cnt[t - off] : 0;
    __syncthreads();
    if (t < BUCK_NODES) cnt[t] += u;
    __syncthreads();
  }
  if (t < BUCK_NODES) {
    const int node = (b << BUCK_SHIFT) + t;
    const int excl = beg + cnt[t] - v;   // start within this bucket's csr range
    lcur[t] = excl;
    if (node < N_NODES) {
      rbeg[node] = excl;
      rend[node] = excl + v;
      dinv[node] = rsqrtf((float)v + 1.0f);   // +1 self-loop
    }
  }
  __syncthreads();
  for (int j = beg + t; j < end; j += 1024) {
    int code = ebuf[j];
    int pos = atomicAdd(&lcur[code >> 17], 1);
    csr[pos] = code & SMASK;
  }
}

// ---------------- Xs = (X @ [P1|P2]) * dinv[i]  ------------------------------
__global__ __launch_bounds__(256) void k_x8(const float* __restrict__ x,
                                            const float* __restrict__ dinv,
                                            const Consts* __restrict__ cst,
                                            float* __restrict__ Xs) {
  __shared__ float xs[32*27];
  const int tid = threadIdx.x;
  const int base = blockIdx.x * 32 * 27;
  for (int j = tid; j < 32*27; j += 256) {
    int g = base + j;
    xs[j] = (g < N_NODES*27) ? x[g] : 0.f;
  }
  __syncthreads();
  int li = tid >> 3, k = tid & 7;
  int node = blockIdx.x * 32 + li;
  if (node < N_NODES) {
    float s = 0.f;
    for (int c = 0; c < 27; ++c) s += xs[li*27+c] * cst->C[c*8+k];
    Xs[node*8+k] = s * dinv[node];
  }
}

// ------ gather pass 1 (float2 lanes, unroll-8): Ys = nd^2(sum+self), dvec ----
__global__ __launch_bounds__(256) void k_gather1(const int* __restrict__ rbeg,
                                                 const int* __restrict__ rend,
                                                 const int* __restrict__ csr,
                                                 const float* __restrict__ dinv,
                                                 const float2* __restrict__ Xs2,
                                                 float2* __restrict__ Ys2,
                                                 float* __restrict__ dvec) {
  int t = blockIdx.x * 256 + threadIdx.x;
  int d = t >> 2, q = t & 3;
  if (d >= N_NODES) return;
  const int beg = rbeg[d], end = rend[d];
  const float nd = dinv[d];
  float2 self = Xs2[d*4 + q];
  float ax = self.x, ay = self.y;
  float dsum = nd;                  // self-loop contribution
  int j = beg;
  for (; j + 8 <= end; j += 8) {    // unroll-8: 8 independent loads in flight
    int s0 = csr[j],   s1 = csr[j+1], s2 = csr[j+2], s3 = csr[j+3];
    int s4 = csr[j+4], s5 = csr[j+5], s6 = csr[j+6], s7 = csr[j+7];
    float2 a0 = Xs2[s0*4+q], a1 = Xs2[s1*4+q], a2 = Xs2[s2*4+q], a3 = Xs2[s3*4+q];
    float2 a4 = Xs2[s4*4+q], a5 = Xs2[s5*4+q], a6 = Xs2[s6*4+q], a7 = Xs2[s7*4+q];
    ax += ((a0.x + a1.x) + (a2.x + a3.x)) + ((a4.x + a5.x) + (a6.x + a7.x));
    ay += ((a0.y + a1.y) + (a2.y + a3.y)) + ((a4.y + a5.y) + (a6.y + a7.y));
    if (q == 0)
      dsum += ((dinv[s0] + dinv[s1]) + (dinv[s2] + dinv[s3]))
            + ((dinv[s4] + dinv[s5]) + (dinv[s6] + dinv[s7]));
  }
  for (; j < end; ++j) {
    int s = csr[j];
    float2 a = Xs2[s*4+q];
    ax += a.x; ay += a.y;
    if (q == 0) dsum += dinv[s];
  }
  float nn = nd * nd;
  Ys2[t] = make_float2(nn * ax, nn * ay);   // = n_d * h1 (pre-scaled for pass 2)
  if (q == 0) dvec[d] = nd * dsum;
}

// ------ gather pass 2 (+bank rows): gall = nd(sum+self) + dvec*u + vg --------
__global__ __launch_bounds__(256) void k_gather2g(const int* __restrict__ rbeg,
                                                  const int* __restrict__ rend,
                                                  const int* __restrict__ csr,
                                                  const float* __restrict__ dinv,
                                                  const float2* __restrict__ Ys2,
                                                  const float* __restrict__ dvec,
                                                  const float* __restrict__ bank,
                                                  const Consts* __restrict__ cst,
                                                  float2* __restrict__ gall2) {
  int t = blockIdx.x * 256 + threadIdx.x;
  int d = t >> 2, q = t & 3;
  if (d >= N_NODES + NB_BANK) return;
  int c0 = 2*q, c1 = 2*q + 1;
  if (d >= N_NODES) {               // bank rows
    int bk = d - N_NODES;
    float sx = cst->vb[c0], sy = cst->vb[c1];
    for (int cc = 0; cc < 27; ++cc) {
      float bv = bank[bk*27+cc];
      sx += bv * cst->Rb[cc*8+c0];
      sy += bv * cst->Rb[cc*8+c1];
    }
    gall2[t] = make_float2(sx, sy);
    return;
  }
  const int beg = rbeg[d], end = rend[d];
  float2 self = Ys2[d*4 + q];
  float ax = self.x, ay = self.y;
  int j = beg;
  for (; j + 8 <= end; j += 8) {
    int s0 = csr[j],   s1 = csr[j+1], s2 = csr[j+2], s3 = csr[j+3];
    int s4 = csr[j+4], s5 = csr[j+5], s6 = csr[j+6], s7 = csr[j+7];
    float2 a0 = Ys2[s0*4+q], a1 = Ys2[s1*4+q], a2 = Ys2[s2*4+q], a3 = Ys2[s3*4+q];
    float2 a4 = Ys2[s4*4+q], a5 = Ys2[s5*4+q], a6 = Ys2[s6*4+q], a7 = Ys2[s7*4+q];
    ax += ((a0.x + a1.x) + (a2.x + a3.x)) + ((a4.x + a5.x) + (a6.x + a7.x));
    ay += ((a0.y + a1.y) + (a2.y + a3.y)) + ((a4.y + a5.y) + (a6.y + a7.y));
  }
  for (; j < end; ++j) {
    float2 a = Ys2[csr[j]*4+q];
    ax += a.x; ay += a.y;
  }
  float nd = dinv[d], dv = dvec[d];
  gall2[t] = make_float2(nd * ax + dv * cst->u[c0] + cst->vg[c0],
                         nd * ay + dv * cst->u[c1] + cst->vg[c1]);
}

// ---------------- online-softmax merge helper --------------------------------
__device__ inline void sm_merge(float4& m1, float4& s1,
                                const float4 m2, const float4 s2) {
  float4 M;
  M.x = fmaxf(m1.x, m2.x); M.y = fmaxf(m1.y, m2.y);
  M.z = fmaxf(m1.z, m2.z); M.w = fmaxf(m1.w, m2.w);
  s1.x = s1.x * expf(m1.x - M.x) + s2.x * expf(m2.x - M.x);
  s1.y = s1.y * expf(m1.y - M.y) + s2.y * expf(m2.y - M.y);
  s1.z = s1.z * expf(m1.z - M.z) + s2.z * expf(m2.z - M.z);
  s1.w = s1.w * expf(m1.w - M.w) + s2.w * expf(m2.w - M.w);
  m1 = M;
}

// ---------------- pair gather + z + per-block online (max,sumexp) ------------
__global__ __launch_bounds__(256) void k_z(const int* __restrict__ node1,
                                           const int* __restrict__ node2,
                                           const float* __restrict__ gall,
                                           float* __restrict__ z,
                                           float4* __restrict__ bs_m,
                                           float4* __restrict__ bs_s) {
  int p = blockIdx.x * 256 + threadIdx.x;
  float4 m = make_float4(-1e30f, -1e30f, -1e30f, -1e30f);
  float4 s = make_float4(0.f, 0.f, 0.f, 0.f);
  if (p < N_PAIRS) {
    int n1 = node1[p], n2 = node2[p];
    const float4 a = *(const float4*)(gall + (size_t)n1*8);
    const float4 b = *(const float4*)(gall + (size_t)n2*8 + 4);
    float4 zv = make_float4(a.x+b.x, a.y+b.y, a.z+b.z, a.w+b.w);
    ((float4*)z)[p] = zv;
    m = zv; s = make_float4(1.f, 1.f, 1.f, 1.f);
  }
  __shared__ float4 lm[256], ls[256];
  lm[threadIdx.x] = m; ls[threadIdx.x] = s;
  __syncthreads();
  for (int st = 128; st > 0; st >>= 1) {
    if (threadIdx.x < st) {
      float4 mm = lm[threadIdx.x], ss = ls[threadIdx.x];
      sm_merge(mm, ss, lm[threadIdx.x + st], ls[threadIdx.x + st]);
      lm[threadIdx.x] = mm; ls[threadIdx.x] = ss;
    }
    __syncthreads();
  }
  if (threadIdx.x == 0) { bs_m[blockIdx.x] = lm[0]; bs_s[blockIdx.x] = ls[0]; }
}

// ---------------- combine block stats -> global (m, S) -----------------------
__global__ __launch_bounds__(256) void k_comb(const float4* __restrict__ bs_m,
                                              const float4* __restrict__ bs_s,
                                              float* __restrict__ gms) {
  float4 m = make_float4(-1e30f, -1e30f, -1e30f, -1e30f);
  float4 s = make_float4(0.f, 0.f, 0.f, 0.f);
  for (int i = threadIdx.x; i < NZBLK; i += 256)
    sm_merge(m, s, bs_m[i], bs_s[i]);
  __shared__ float4 lm[256], ls[256];
  lm[threadIdx.x] = m; ls[threadIdx.x] = s;
  __syncthreads();
  for (int st = 128; st > 0; st >>= 1) {
    if (threadIdx.x < st) {
      float4 mm = lm[threadIdx.x], ss = ls[threadIdx.x];
      sm_merge(mm, ss, lm[threadIdx.x + st], ls[threadIdx.x + st]);
      lm[threadIdx.x] = mm; ls[threadIdx.x] = ss;
    }
    __syncthreads();
  }
  if (threadIdx.x == 0) {
    float4 M = lm[0], S = ls[0];
    gms[0] = M.x; gms[1] = M.y; gms[2] = M.z; gms[3] = M.w;
    gms[4] = S.x; gms[5] = S.y; gms[6] = S.z; gms[7] = S.w;
  }
}

// ---------------- normalize --------------------------------------------------
__global__ __launch_bounds__(256) void k_final(const float* __restrict__ z,
                                               const float* __restrict__ gms,
                                               float* __restrict__ out) {
  int p = blockIdx.x * 256 + threadIdx.x;
  if (p < N_PAIRS) {
    float m0 = gms[0], m1 = gms[1], m2 = gms[2], m3 = gms[3];
    float i0 = 1.f / gms[4], i1 = 1.f / gms[5];
    float i2 = 1.f / gms[6], i3 = 1.f / gms[7];
    float4 zv = ((const float4*)z)[p];
    float4 o = make_float4(expf(zv.x - m0) * i0, expf(zv.y - m1) * i1,
                           expf(zv.z - m2) * i2, expf(zv.w - m3) * i3);
    ((float4*)out)[p] = o;
  }
}

extern "C" void kernel_launch(void* const* d_in, const int* in_sizes, int n_in,
                              void* d_out, int out_size, void* d_ws, size_t ws_size,
                              hipStream_t stream) {
  const float* x    = (const float*)d_in[0];
  const float* bank = (const float*)d_in[1];
  const float* W1   = (const float*)d_in[2];
  const float* b1   = (const float*)d_in[3];
  const float* W2   = (const float*)d_in[4];
  const float* b2   = (const float*)d_in[5];
  const float* Wb   = (const float*)d_in[6];
  const float* bb   = (const float*)d_in[7];
  const float* Wf1  = (const float*)d_in[8];
  const float* bf1  = (const float*)d_in[9];
  const float* Wf2  = (const float*)d_in[10];
  const float* bf2  = (const float*)d_in[11];
  const float* Wf3  = (const float*)d_in[12];
  const float* bf3  = (const float*)d_in[13];
  const int* ei     = (const int*)d_in[14];
  const int* node1  = (const int*)d_in[15];
  const int* node2  = (const int*)d_in[16];
  float* out = (float*)d_out;

  char* w = (char*)d_ws;
  size_t off = 0;
  auto take = [&](size_t bytes) -> char* {
    char* p = w + off;
    off = (off + bytes + 255) & ~(size_t)255;
    return p;
  };
  Consts* cst    = (Consts*)take(sizeof(Consts));
  int*    bcnt   = (int*)take(NBUCK * 4);
  float*  dinv   = (float*)take(N_NODES * 4);
  int*    rbeg   = (int*)take(N_NODES * 4);
  int*    rend   = (int*)take(N_NODES * 4);
  int*    csr    = (int*)take((size_t)NBUCK * BCAP * 4);
  float*  Xs     = (float*)take((size_t)N_NODES * 8 * 4);
  float*  Ys     = (float*)take((size_t)N_NODES * 8 * 4);
  float*  dvec   = (float*)take(N_NODES * 4);
  float*  gall   = (float*)take((size_t)(N_NODES + NB_BANK) * 8 * 4);
  // ebuf (build phase) and z (pair phase) have disjoint lifetimes -> share.
  char*   shreg  = take((size_t)NBUCK * BCAP * 4 > (size_t)N_PAIRS * 16
                        ? (size_t)NBUCK * BCAP * 4 : (size_t)N_PAIRS * 16);
  int*    ebuf   = (int*)shreg;
  float*  z      = (float*)shreg;
  float4* bs_m   = (float4*)take((size_t)NZBLK * 16);
  float4* bs_s   = (float4*)take((size_t)NZBLK * 16);
  float*  gms    = (float*)take(32);

  hipMemsetAsync(bcnt, 0, NBUCK * 4, stream);

  // single-pass bucket scatter + (extra block) weight-chain precompute
  k_scatter<<<NSCAT + 1, 1024, 0, stream>>>(ei, bcnt, ebuf, W1, b1, W2, b2,
                                            Wb, bb, Wf1, bf1, Wf2, bf2,
                                            Wf3, bf3, cst);
  // per-bucket: degree/dinv/rbeg/rend + CSR fill
  k_degfill<<<NBUCK, 1024, 0, stream>>>(bcnt, ebuf, dinv, rbeg, rend, csr);
  // features
  k_x8<<<(N_NODES + 31) / 32, 256, 0, stream>>>(x, dinv, cst, Xs);
  // propagation (atomic-free float2 gathers, unroll-8)
  k_gather1<<<(N_NODES * 4 + 255) / 256, 256, 0, stream>>>(
      rbeg, rend, csr, dinv, (const float2*)Xs, (float2*)Ys, dvec);
  k_gather2g<<<((N_NODES + NB_BANK) * 4 + 255) / 256, 256, 0, stream>>>(
      rbeg, rend, csr, dinv, (const float2*)Ys, dvec, bank, cst, (float2*)gall);
  // pair phase: z + block stats, single-block combine, normalize
  k_z<<<NZBLK, 256, 0, stream>>>(node1, node2, gall, z, bs_m, bs_s);
  k_comb<<<1, 256, 0, stream>>>(bs_m, bs_s, gms);
  k_final<<<NZBLK, 256, 0, stream>>>(z, gms, out);
}